// Round 1
// baseline (531.342 us; speedup 1.0000x reference)
//
#include <hip/hip_runtime.h>
#include <cstdint>
#include <cstddef>

#define NR 8192
#define DD 128
#define GAT_ALPHA 0.2f

typedef short short8 __attribute__((ext_vector_type(8)));
typedef float f32x16 __attribute__((ext_vector_type(16)));

__device__ __forceinline__ unsigned short f2bf(float f){
  unsigned u = __float_as_uint(f);
  u += 0x7fffu + ((u >> 16) & 1u);           // RNE round to bf16
  return (unsigned short)(u >> 16);
}
__device__ __forceinline__ unsigned fenc(float f){   // monotone float->uint
  unsigned u = __float_as_uint(f);
  return (u & 0x80000000u) ? ~u : (u | 0x80000000u);
}
__device__ __forceinline__ float fdec(unsigned e){
  unsigned u = (e & 0x80000000u) ? (e ^ 0x80000000u) : ~e;
  return __uint_as_float(u);
}

// ---------------- k1: h = input @ W (fp32) ; also hT (bf16, transposed) -----
__global__ __launch_bounds__(256) void k_gemm_h(
    const float* __restrict__ in, const float* __restrict__ W,
    float* __restrict__ h, unsigned short* __restrict__ hT)
{
  const int g = blockIdx.x * 256 + threadIdx.x;   // 262144 threads
  const int r  = g >> 5;                           // row 0..8191
  const int cg = g & 31;                           // col-quad 0..31
  const float4* inr = (const float4*)(in + (size_t)r * DD);
  const float4* W4  = (const float4*)W;            // W[k][c] row-major
  float4 acc = make_float4(0.f, 0.f, 0.f, 0.f);
  #pragma unroll 4
  for (int k4 = 0; k4 < 32; ++k4){
    float4 iv = inr[k4];
    float4 wv;
    wv = W4[(k4*4+0)*32 + cg];
    acc.x = fmaf(iv.x, wv.x, acc.x); acc.y = fmaf(iv.x, wv.y, acc.y);
    acc.z = fmaf(iv.x, wv.z, acc.z); acc.w = fmaf(iv.x, wv.w, acc.w);
    wv = W4[(k4*4+1)*32 + cg];
    acc.x = fmaf(iv.y, wv.x, acc.x); acc.y = fmaf(iv.y, wv.y, acc.y);
    acc.z = fmaf(iv.y, wv.z, acc.z); acc.w = fmaf(iv.y, wv.w, acc.w);
    wv = W4[(k4*4+2)*32 + cg];
    acc.x = fmaf(iv.z, wv.x, acc.x); acc.y = fmaf(iv.z, wv.y, acc.y);
    acc.z = fmaf(iv.z, wv.z, acc.z); acc.w = fmaf(iv.z, wv.w, acc.w);
    wv = W4[(k4*4+3)*32 + cg];
    acc.x = fmaf(iv.w, wv.x, acc.x); acc.y = fmaf(iv.w, wv.y, acc.y);
    acc.z = fmaf(iv.w, wv.z, acc.z); acc.w = fmaf(iv.w, wv.w, acc.w);
  }
  ((float4*)(h + (size_t)r * DD))[cg] = acc;
  const int c0 = cg * 4;
  hT[(size_t)(c0+0)*NR + r] = f2bf(acc.x);
  hT[(size_t)(c0+1)*NR + r] = f2bf(acc.y);
  hT[(size_t)(c0+2)*NR + r] = f2bf(acc.z);
  hT[(size_t)(c0+3)*NR + r] = f2bf(acc.w);
}

// ---------------- k2: f1 = h@a1, f2 = h@a2, gmax = max(f2) ------------------
__global__ __launch_bounds__(256) void k_f12(
    const float* __restrict__ h, const float* __restrict__ a,
    float* __restrict__ f1, float* __restrict__ f2, unsigned* __restrict__ gmax)
{
  const int w = threadIdx.x >> 6, lane = threadIdx.x & 63;
  const int row = blockIdx.x * 4 + w;
  const float* hr = h + (size_t)row * DD;
  float h0 = hr[lane], h1 = hr[lane + 64];
  float s1 = fmaf(h0, a[lane],       h1 * a[lane + 64]);
  float s2 = fmaf(h0, a[128 + lane], h1 * a[192 + lane]);
  #pragma unroll
  for (int off = 32; off; off >>= 1){
    s1 += __shfl_xor(s1, off, 64);
    s2 += __shfl_xor(s2, off, 64);
  }
  if (lane == 0){
    f1[row] = s1;
    f2[row] = s2;
    atomicMax(gmax, fenc(s2));
  }
}

// ---------------- k3: masked-softmax-weighted GEMM (the big one) ------------
// grid (8 ksplits, 64 rowblocks), 256 threads = 4 waves, wave owns 32 rows.
// P generated directly in MFMA A-fragment layout from adj + f1 + f2; analytic
// softmax shift m_i = lrelu(f1_i + max_j f2_j) makes K-splits associative.
__global__ __launch_bounds__(256, 2) void k_attn(
    const int* __restrict__ adj, const unsigned short* __restrict__ hT,
    const float* __restrict__ f1, const float* __restrict__ f2,
    const unsigned* __restrict__ gmax,
    float* __restrict__ O, float* __restrict__ l)
{
  const int s    = blockIdx.x;        // ksplit 0..7
  const int rb   = blockIdx.y;        // rowblock 0..63
  const int tid  = threadIdx.x;
  const int w    = tid >> 6;
  const int lane = tid & 63;
  const int half = lane >> 5;
  const int lm   = lane & 31;
  const int i    = rb * 128 + w * 32 + lm;   // row this lane generates P for
  const int k0   = s * 1024;

  __shared__ float4 sHT[2][1024];     // 16KB x2: hT chunk, XOR-swizzled 16B blocks
  __shared__ float  sF2[2][64];

  const float F2MAX = fdec(*gmax);
  const float f1i = f1[i];
  const float mm = f1i + F2MAX;
  const float mi = fmaxf(mm, GAT_ALPHA * mm);   // lrelu(f1+F2MAX): safe row-max bound

  f32x16 acc[4];
  #pragma unroll
  for (int ct = 0; ct < 4; ++ct)
    #pragma unroll
    for (int rr = 0; rr < 16; ++rr) acc[ct][rr] = 0.f;
  float lp = 0.f;

  const int* arow = adj + (size_t)i * NR + k0 + half * 8;

  int4 av[8], nv[8];

  // stage hT chunk (swizzled) + f2 chunk into LDS buffer `buf` for chunk kc
  auto stage = [&](int buf, int kc){
    const size_t kb = (size_t)(k0 + kc * 64);
    #pragma unroll
    for (int q = 0; q < 4; ++q){
      int lin = q * 256 + tid;        // 16B-block index 0..1023
      int c    = lin >> 3;            // hT row (col of h) 0..127
      int blk  = lin & 7;
      int sblk = blk ^ (c & 7);       // XOR swizzle to spread banks
      float4 v = *(const float4*)(hT + (size_t)c * NR + kb + (size_t)sblk * 8);
      sHT[buf][lin] = v;
    }
    if (tid < 64) sF2[buf][tid] = f2[kb + tid];
  };
  auto loadAdj = [&](int kc, int4* dst){
    const int4* ap = (const int4*)(arow + (size_t)kc * 64);
    #pragma unroll
    for (int ks = 0; ks < 4; ++ks){ dst[2*ks] = ap[ks*4]; dst[2*ks+1] = ap[ks*4+1]; }
  };

  stage(0, 0);
  loadAdj(0, av);
  __syncthreads();

  int buf = 0;
  for (int kc = 0; kc < 16; ++kc){
    if (kc < 15){
      stage(buf ^ 1, kc + 1);   // async-ish prefetch into other LDS buffer
      loadAdj(kc + 1, nv);      // register prefetch of next adj chunk
    }

    // ---- generate P in A-fragment layout: A[m=lm][k=ks*16 + half*8 + j] ----
    short8 afr[4];
    const float4* f2v = (const float4*)(&sF2[buf][0]);
    #pragma unroll
    for (int ks = 0; ks < 4; ++ks){
      float4 fA = f2v[ks*4 + half*2];
      float4 fB = f2v[ks*4 + half*2 + 1];
      int4 aA = av[2*ks], aB = av[2*ks+1];
      float fv[8] = {fA.x, fA.y, fA.z, fA.w, fB.x, fB.y, fB.z, fB.w};
      int   ai[8] = {aA.x, aA.y, aA.z, aA.w, aB.x, aB.y, aB.z, aB.w};
      #pragma unroll
      for (int j = 0; j < 8; ++j){
        float t = f1i + fv[j];
        float u = fmaxf(t, GAT_ALPHA * t);     // leaky relu
        float p = __expf(u - mi);              // <= 1, no overflow
        p = (ai[j] > 0) ? p : 0.f;             // adjacency mask
        lp += p;
        afr[ks][j] = (short)f2bf(p);
      }
    }

    // ---- 16 MFMAs: 4 K-steps x 4 col-tiles, B from swizzled LDS ----
    #pragma unroll
    for (int ks = 0; ks < 4; ++ks){
      #pragma unroll
      for (int ct = 0; ct < 4; ++ct){
        int c = ct * 32 + lm;
        int blkb = (ks * 2 + half) ^ (c & 7);
        short8 bfr = ((const short8*)(&sHT[buf][0]))[c * 8 + blkb];
        acc[ct] = __builtin_amdgcn_mfma_f32_32x32x16_bf16(afr[ks], bfr, acc[ct], 0, 0, 0);
      }
    }

    __syncthreads();
    buf ^= 1;
    if (kc < 15){
      #pragma unroll
      for (int q = 0; q < 8; ++q) av[q] = nv[q];
    }
  }

  // ---- epilogue: accumulate partials (K-splits are associative) ----
  lp += __shfl_xor(lp, 32, 64);
  if (half == 0)
    __hip_atomic_fetch_add(&l[i], lp, __ATOMIC_RELAXED, __HIP_MEMORY_SCOPE_AGENT);

  #pragma unroll
  for (int ct = 0; ct < 4; ++ct){
    #pragma unroll
    for (int rr = 0; rr < 16; ++rr){
      int row = rb * 128 + w * 32 + (rr & 3) + 8 * (rr >> 2) + 4 * half;
      int col = ct * 32 + lm;
      __hip_atomic_fetch_add(&O[(size_t)row * DD + col], acc[ct][rr],
                             __ATOMIC_RELAXED, __HIP_MEMORY_SCOPE_AGENT);
    }
  }
}

// ---------------- k4: out = elu(O / l) --------------------------------------
__global__ __launch_bounds__(256) void k_out(
    const float* __restrict__ O, const float* __restrict__ l,
    float* __restrict__ out)
{
  const int gid = blockIdx.x * 256 + threadIdx.x;   // float4 index, 262144 total
  const int row = gid >> 5;
  const float inv = 1.0f / l[row];
  float4 o = ((const float4*)O)[gid];
  float4 r;
  float x;
  x = o.x * inv; r.x = x > 0.f ? x : (__expf(x) - 1.f);
  x = o.y * inv; r.y = x > 0.f ? x : (__expf(x) - 1.f);
  x = o.z * inv; r.z = x > 0.f ? x : (__expf(x) - 1.f);
  x = o.w * inv; r.w = x > 0.f ? x : (__expf(x) - 1.f);
  ((float4*)out)[gid] = r;
}

// ---------------- launcher ---------------------------------------------------
extern "C" void kernel_launch(void* const* d_in, const int* in_sizes, int n_in,
                              void* d_out, int out_size, void* d_ws, size_t ws_size,
                              hipStream_t stream)
{
  const float* in  = (const float*)d_in[0];
  const int*   adj = (const int*)  d_in[1];
  const float* W   = (const float*)d_in[2];
  const float* a   = (const float*)d_in[3];
  float* out = (float*)d_out;

  char* ws = (char*)d_ws;
  // layout (bytes):
  //   O    [0,        4194304)  fp32 [8192][128]   (zeroed)
  //   l    [4194304,  4227072)  fp32 [8192]        (zeroed)
  //   gmax [4227072,  4227076)  uint               (zeroed)
  //   hT   [4227328,  6324480)  bf16 [128][8192]
  //   h    [6324480, 10518784)  fp32 [8192][128]
  //   f1   [10518784,10551552)  fp32 [8192]
  //   f2   [10551552,10584320)  fp32 [8192]
  float*          O    = (float*)         (ws + 0);
  float*          l    = (float*)         (ws + 4194304);
  unsigned*       gmax = (unsigned*)      (ws + 4227072);
  unsigned short* hT   = (unsigned short*)(ws + 4227328);
  float*          h    = (float*)         (ws + 6324480);
  float*          f1   = (float*)         (ws + 10518784);
  float*          f2   = (float*)         (ws + 10551552);

  hipMemsetAsync(d_ws, 0, 4227328, stream);   // zero O, l, gmax

  hipLaunchKernelGGL(k_gemm_h, dim3(1024), dim3(256), 0, stream, in, W, h, hT);
  hipLaunchKernelGGL(k_f12,    dim3(2048), dim3(256), 0, stream, h, a, f1, f2, gmax);
  hipLaunchKernelGGL(k_attn,   dim3(8, 64), dim3(256), 0, stream,
                     adj, hT, f1, f2, gmax, O, l);
  hipLaunchKernelGGL(k_out,    dim3(1024), dim3(256), 0, stream, O, l, out);
}

// Round 3
// 448.796 us; speedup vs baseline: 1.1839x; 1.1839x over previous
//
#include <hip/hip_runtime.h>
#include <cstdint>
#include <cstddef>

#define NR 8192
#define DD 128
#define NSPLIT 8
#define GAT_ALPHA 0.2f

typedef short short8 __attribute__((ext_vector_type(8)));
typedef unsigned short ushort8 __attribute__((ext_vector_type(8)));
typedef float f32x4 __attribute__((ext_vector_type(4)));
typedef int i32x4 __attribute__((ext_vector_type(4)));

__device__ __forceinline__ unsigned short f2bf(float f){
  unsigned u = __float_as_uint(f);
  u += 0x7fffu + ((u >> 16) & 1u);           // RNE round to bf16
  return (unsigned short)(u >> 16);
}
__device__ __forceinline__ unsigned fenc(float f){   // monotone float->uint
  unsigned u = __float_as_uint(f);
  return (u & 0x80000000u) ? ~u : (u | 0x80000000u);
}
__device__ __forceinline__ float fdec(unsigned e){
  unsigned u = (e & 0x80000000u) ? (e ^ 0x80000000u) : ~e;
  return __uint_as_float(u);
}
__device__ __forceinline__ void gload_lds16(const void* g, void* l){
  __builtin_amdgcn_global_load_lds(
      (const __attribute__((address_space(1))) unsigned*)g,
      (__attribute__((address_space(3))) unsigned*)l, 16, 0, 0);
}

// ---- k1: h = in@W (regs only), f1=h@a1, f2=h@a2, gmax=max(f2), hT=bf16(h)^T
__global__ __launch_bounds__(256) void k_pre(
    const float* __restrict__ in, const float* __restrict__ W,
    const float* __restrict__ a,
    unsigned short* __restrict__ hT, float* __restrict__ f1,
    float* __restrict__ f2, unsigned* __restrict__ gmax)
{
  __shared__ __align__(16) unsigned short sT[128][8];   // [col][row-in-block]
  const int tid = threadIdx.x;
  const int g = blockIdx.x * 256 + tid;
  const int r  = g >> 5;                    // row 0..8191 (8 rows per block)
  const int cg = g & 31;                    // col-quad
  const float4* inr = (const float4*)(in + (size_t)r * DD);
  const float4* W4  = (const float4*)W;
  float4 acc = make_float4(0.f, 0.f, 0.f, 0.f);
  #pragma unroll 4
  for (int k4 = 0; k4 < 32; ++k4){
    float4 iv = inr[k4];
    float4 wv;
    wv = W4[(k4*4+0)*32 + cg];
    acc.x = fmaf(iv.x, wv.x, acc.x); acc.y = fmaf(iv.x, wv.y, acc.y);
    acc.z = fmaf(iv.x, wv.z, acc.z); acc.w = fmaf(iv.x, wv.w, acc.w);
    wv = W4[(k4*4+1)*32 + cg];
    acc.x = fmaf(iv.y, wv.x, acc.x); acc.y = fmaf(iv.y, wv.y, acc.y);
    acc.z = fmaf(iv.y, wv.z, acc.z); acc.w = fmaf(iv.y, wv.w, acc.w);
    wv = W4[(k4*4+2)*32 + cg];
    acc.x = fmaf(iv.z, wv.x, acc.x); acc.y = fmaf(iv.z, wv.y, acc.y);
    acc.z = fmaf(iv.z, wv.z, acc.z); acc.w = fmaf(iv.z, wv.w, acc.w);
    wv = W4[(k4*4+3)*32 + cg];
    acc.x = fmaf(iv.w, wv.x, acc.x); acc.y = fmaf(iv.w, wv.y, acc.y);
    acc.z = fmaf(iv.w, wv.z, acc.z); acc.w = fmaf(iv.w, wv.w, acc.w);
  }
  // f1/f2 partial dot over this thread's 4 cols, reduce across 32-lane group
  const int c0 = cg * 4;
  float s1 = acc.x*a[c0] + acc.y*a[c0+1] + acc.z*a[c0+2] + acc.w*a[c0+3];
  float s2 = acc.x*a[128+c0] + acc.y*a[128+c0+1] + acc.z*a[128+c0+2] + acc.w*a[128+c0+3];
  #pragma unroll
  for (int off = 16; off; off >>= 1){
    s1 += __shfl_xor(s1, off, 64);
    s2 += __shfl_xor(s2, off, 64);
  }
  if ((tid & 31) == 0){
    f1[r] = s1; f2[r] = s2;
    atomicMax(gmax, fenc(s2));
  }
  // transpose to hT via LDS (coalesce the writes to 16B/lane)
  const int rl = r & 7;
  sT[c0+0][rl] = f2bf(acc.x);
  sT[c0+1][rl] = f2bf(acc.y);
  sT[c0+2][rl] = f2bf(acc.z);
  sT[c0+3][rl] = f2bf(acc.w);
  __syncthreads();
  if (tid < 128){
    ushort8 v = *(const ushort8*)&sT[tid][0];
    *(ushort8*)(hT + (size_t)tid * NR + blockIdx.x * 8) = v;
  }
}

// ---- k2: masked-softmax-weighted GEMM, 16x16x32 MFMA, split-K partials ----
// grid (8 ksplits, 128 rowblocks) x 256 thr; wave owns 16 rows x 128 cols.
__global__ __launch_bounds__(256, 4) void k_attn(
    const int* __restrict__ adj, const unsigned short* __restrict__ hT,
    const float* __restrict__ f1, const float* __restrict__ f2,
    const unsigned* __restrict__ gmax,
    float* __restrict__ Opart, float* __restrict__ lpart)
{
  const int s    = blockIdx.x;        // ksplit 0..7  (1024 k each, 16 chunks)
  const int rb   = blockIdx.y;        // rowblock 0..127 (64 rows)
  const int tid  = threadIdx.x;
  const int w    = tid >> 6;
  const int lane = tid & 63;
  const int quad = lane >> 4;
  const int m    = lane & 15;
  const int i    = rb * 64 + w * 16 + m;    // this lane's P row
  const int k0   = s * 1024;

  __shared__ float4 sHT[2][1024];           // 16KB/buf: 128 cols x 8 k-octets, XOR swizzled
  __shared__ __align__(16) float sF2[2][64];

  const float F2MAX = fdec(*gmax);
  const float f1i = f1[i];
  const float mm = f1i + F2MAX;
  const float mi = fmaxf(mm, GAT_ALPHA * mm);  // lrelu(f1+maxf2) >= row max, exact bound
  const float L2E = 1.44269504089f;
  const float miL = mi * L2E;

  f32x4 acc[8];
  #pragma unroll
  for (int ct = 0; ct < 8; ++ct){ acc[ct][0]=0.f; acc[ct][1]=0.f; acc[ct][2]=0.f; acc[ct][3]=0.f; }
  float lp = 0.f;

  const int* arow = adj + (size_t)i * NR + k0 + quad * 8;

  i32x4 av[4], nv[4];

  auto stage = [&](int buf, int kc){
    const size_t kb = (size_t)(k0 + kc * 64);
    #pragma unroll
    for (int q = 0; q < 4; ++q){
      int lin  = q * 256 + tid;       // 16B block index 0..1023
      int c    = lin >> 3;            // hT row (feature col) 0..127
      int blk  = lin & 7;
      int sblk = blk ^ (c & 7);       // XOR swizzle
      gload_lds16(hT + (size_t)c * NR + kb + (size_t)sblk * 8, &sHT[buf][lin]);
    }
    if (tid < 64) sF2[buf][tid] = f2[kb + tid];
  };
  auto loadAdj = [&](int kc, i32x4* dst){
    const i32x4* p0 = (const i32x4*)(arow + kc * 64);
    #pragma unroll
    for (int ks = 0; ks < 2; ++ks){
      dst[2*ks]   = __builtin_nontemporal_load(p0 + ks*8);
      dst[2*ks+1] = __builtin_nontemporal_load(p0 + ks*8 + 1);
    }
  };

  stage(0, 0);
  loadAdj(0, av);
  __syncthreads();

  int buf = 0;
  for (int kc = 0; kc < 16; ++kc){
    if (kc < 15){
      stage(buf ^ 1, kc + 1);         // async global->LDS into other buffer
      loadAdj(kc + 1, nv);            // register prefetch of next adj
    }

    // P in A-frag layout: A[m=lane&15][k = ks*32 + quad*8 + j]
    short8 afr[2];
    const float4* f2v = (const float4*)&sF2[buf][0];
    #pragma unroll
    for (int ks = 0; ks < 2; ++ks){
      float4 fA = f2v[ks*8 + quad*2];
      float4 fB = f2v[ks*8 + quad*2 + 1];
      i32x4 aA = av[2*ks], aB = av[2*ks+1];
      float fv[8] = {fA.x, fA.y, fA.z, fA.w, fB.x, fB.y, fB.z, fB.w};
      int   ai[8] = {aA[0], aA[1], aA[2], aA[3], aB[0], aB[1], aB[2], aB[3]};
      short8 fr;
      #pragma unroll
      for (int j = 0; j < 8; ++j){
        float t = f1i + fv[j];
        float u = fmaxf(t, GAT_ALPHA * t);       // leaky relu
        float p = __builtin_amdgcn_exp2f(fmaf(u, L2E, -miL));   // exp(u-mi), <=1
        p = (ai[j] > 0) ? p : 0.f;
        lp += p;
        fr[j] = (short)f2bf(p);
      }
      afr[ks] = fr;
    }

    // 16 MFMAs: 2 K-steps x 8 col-tiles of 16
    const short8* sB = (const short8*)&sHT[buf][0];
    #pragma unroll
    for (int ks = 0; ks < 2; ++ks){
      #pragma unroll
      for (int ct = 0; ct < 8; ++ct){
        int c = ct * 16 + m;
        int o = (ks * 4 + quad) ^ (c & 7);
        short8 bfr = sB[c * 8 + o];
        acc[ct] = __builtin_amdgcn_mfma_f32_16x16x32_bf16(afr[ks], bfr, acc[ct], 0, 0, 0);
      }
    }

    __syncthreads();
    buf ^= 1;
    if (kc < 15){
      #pragma unroll
      for (int q = 0; q < 4; ++q) av[q] = nv[q];
    }
  }

  // ---- epilogue: per-split partial stores (no atomics) ----
  lp += __shfl_xor(lp, 16, 64);
  lp += __shfl_xor(lp, 32, 64);
  if (lane < 16) lpart[(size_t)s * NR + rb * 64 + w * 16 + m] = lp;

  float* op = Opart + (size_t)s * NR * DD;
  #pragma unroll
  for (int ct = 0; ct < 8; ++ct){
    int col = ct * 16 + m;
    #pragma unroll
    for (int reg = 0; reg < 4; ++reg){
      int row = rb * 64 + w * 16 + quad * 4 + reg;   // C layout: col=lane&15, row=quad*4+reg
      __builtin_nontemporal_store(acc[ct][reg], op + (size_t)row * DD + col);
    }
  }
}

// ---- k3: reduce split-K partials, out = elu(O / l) ----
__global__ __launch_bounds__(256) void k_out(
    const float* __restrict__ Opart, const float* __restrict__ lpart,
    float* __restrict__ out)
{
  const int gid = blockIdx.x * 256 + threadIdx.x;   // float4 index, 262144 total
  const int row = gid >> 5;
  float lsum = 0.f;
  float4 o = make_float4(0.f, 0.f, 0.f, 0.f);
  const float4* O4 = (const float4*)Opart;
  #pragma unroll
  for (int s = 0; s < NSPLIT; ++s){
    lsum += lpart[(size_t)s * NR + row];
    float4 v = O4[(size_t)s * (NR * DD / 4) + gid];
    o.x += v.x; o.y += v.y; o.z += v.z; o.w += v.w;
  }
  const float inv = 1.0f / lsum;
  float4 r; float x;
  x = o.x * inv; r.x = x > 0.f ? x : (__expf(x) - 1.f);
  x = o.y * inv; r.y = x > 0.f ? x : (__expf(x) - 1.f);
  x = o.z * inv; r.z = x > 0.f ? x : (__expf(x) - 1.f);
  x = o.w * inv; r.w = x > 0.f ? x : (__expf(x) - 1.f);
  ((float4*)out)[gid] = r;
}

// ---- launcher ----
extern "C" void kernel_launch(void* const* d_in, const int* in_sizes, int n_in,
                              void* d_out, int out_size, void* d_ws, size_t ws_size,
                              hipStream_t stream)
{
  const float* in  = (const float*)d_in[0];
  const int*   adj = (const int*)  d_in[1];
  const float* W   = (const float*)d_in[2];
  const float* a   = (const float*)d_in[3];
  float* out = (float*)d_out;

  char* ws = (char*)d_ws;
  // layout (bytes):
  //   gmax  [0, 4)
  //   f1    [4096,   36864)                 fp32 [8192]
  //   f2    [36864,  69632)                 fp32 [8192]
  //   hT    [1048576, 3145728)              bf16 [128][8192]
  //   Opart [4194304, 4194304+33554432)     fp32 [8][8192][128]
  //   lpart [37748736, 38010880)            fp32 [8][8192]
  unsigned*       gmax  = (unsigned*)      (ws + 0);
  float*          f1    = (float*)         (ws + 4096);
  float*          f2    = (float*)         (ws + 36864);
  unsigned short* hT    = (unsigned short*)(ws + 1048576);
  float*          Opart = (float*)         (ws + 4194304);
  float*          lpart = (float*)         (ws + 37748736);

  (void)hipMemsetAsync(gmax, 0, 4, stream);   // fenc-space -inf

  hipLaunchKernelGGL(k_pre,  dim3(1024),     dim3(256), 0, stream, in, W, a, hT, f1, f2, gmax);
  hipLaunchKernelGGL(k_attn, dim3(8, 128),   dim3(256), 0, stream, adj, hT, f1, f2, gmax, Opart, lpart);
  hipLaunchKernelGGL(k_out,  dim3(1024),     dim3(256), 0, stream, Opart, lpart, out);
}

// Round 4
// 446.863 us; speedup vs baseline: 1.1890x; 1.0043x over previous
//
#include <hip/hip_runtime.h>
#include <cstdint>
#include <cstddef>

#define NR 8192
#define DD 128
#define NSPLIT 8
#define GAT_ALPHA 0.2f

typedef short short8 __attribute__((ext_vector_type(8)));
typedef unsigned short ushort8 __attribute__((ext_vector_type(8)));
typedef float f32x4 __attribute__((ext_vector_type(4)));
typedef int i32x4 __attribute__((ext_vector_type(4)));

__device__ __forceinline__ unsigned short f2bf(float f){
  unsigned u = __float_as_uint(f);
  u += 0x7fffu + ((u >> 16) & 1u);           // RNE round to bf16
  return (unsigned short)(u >> 16);
}
__device__ __forceinline__ unsigned fenc(float f){   // monotone float->uint
  unsigned u = __float_as_uint(f);
  return (u & 0x80000000u) ? ~u : (u | 0x80000000u);
}
__device__ __forceinline__ float fdec(unsigned e){
  unsigned u = (e & 0x80000000u) ? (e ^ 0x80000000u) : ~e;
  return __uint_as_float(u);
}
__device__ __forceinline__ void gload_lds16(const void* g, void* l){
  __builtin_amdgcn_global_load_lds(
      (const __attribute__((address_space(1))) unsigned*)g,
      (__attribute__((address_space(3))) unsigned*)l, 16, 0, 0);
}

// ---- k1: h = in@W (regs only), f1=h@a1, f2=h@a2, gmax=max(f2), hT=bf16(h)^T
__global__ __launch_bounds__(256) void k_pre(
    const float* __restrict__ in, const float* __restrict__ W,
    const float* __restrict__ a,
    unsigned short* __restrict__ hT, float* __restrict__ f1,
    float* __restrict__ f2, unsigned* __restrict__ gmax)
{
  __shared__ __align__(16) unsigned short sT[128][8];   // [col][row-in-block]
  const int tid = threadIdx.x;
  const int g = blockIdx.x * 256 + tid;
  const int r  = g >> 5;                    // row 0..8191 (8 rows per block)
  const int cg = g & 31;                    // col-quad
  const float4* inr = (const float4*)(in + (size_t)r * DD);
  const float4* W4  = (const float4*)W;
  float4 acc = make_float4(0.f, 0.f, 0.f, 0.f);
  #pragma unroll 4
  for (int k4 = 0; k4 < 32; ++k4){
    float4 iv = inr[k4];
    float4 wv;
    wv = W4[(k4*4+0)*32 + cg];
    acc.x = fmaf(iv.x, wv.x, acc.x); acc.y = fmaf(iv.x, wv.y, acc.y);
    acc.z = fmaf(iv.x, wv.z, acc.z); acc.w = fmaf(iv.x, wv.w, acc.w);
    wv = W4[(k4*4+1)*32 + cg];
    acc.x = fmaf(iv.y, wv.x, acc.x); acc.y = fmaf(iv.y, wv.y, acc.y);
    acc.z = fmaf(iv.y, wv.z, acc.z); acc.w = fmaf(iv.y, wv.w, acc.w);
    wv = W4[(k4*4+2)*32 + cg];
    acc.x = fmaf(iv.z, wv.x, acc.x); acc.y = fmaf(iv.z, wv.y, acc.y);
    acc.z = fmaf(iv.z, wv.z, acc.z); acc.w = fmaf(iv.z, wv.w, acc.w);
    wv = W4[(k4*4+3)*32 + cg];
    acc.x = fmaf(iv.w, wv.x, acc.x); acc.y = fmaf(iv.w, wv.y, acc.y);
    acc.z = fmaf(iv.w, wv.z, acc.z); acc.w = fmaf(iv.w, wv.w, acc.w);
  }
  const int c0 = cg * 4;
  float s1 = acc.x*a[c0] + acc.y*a[c0+1] + acc.z*a[c0+2] + acc.w*a[c0+3];
  float s2 = acc.x*a[128+c0] + acc.y*a[128+c0+1] + acc.z*a[128+c0+2] + acc.w*a[128+c0+3];
  #pragma unroll
  for (int off = 16; off; off >>= 1){
    s1 += __shfl_xor(s1, off, 64);
    s2 += __shfl_xor(s2, off, 64);
  }
  if ((tid & 31) == 0){
    f1[r] = s1; f2[r] = s2;
    atomicMax(gmax, fenc(s2));
  }
  const int rl = r & 7;
  sT[c0+0][rl] = f2bf(acc.x);
  sT[c0+1][rl] = f2bf(acc.y);
  sT[c0+2][rl] = f2bf(acc.z);
  sT[c0+3][rl] = f2bf(acc.w);
  __syncthreads();
  if (tid < 128){
    ushort8 v = *(const ushort8*)&sT[tid][0];
    *(ushort8*)(hT + (size_t)tid * NR + blockIdx.x * 8) = v;
  }
}

// ---- k2: masked-softmax-weighted GEMM, phased LDS staging, barrier-free chunks
// grid (8 ksplits, 64 rowblocks) x 512 thr (8 waves); wave owns 16 rows x 128 cols.
// hT k-slice staged in 4 phases of 256k x 128c = 64KB; within a phase the 4
// 64-k chunks run with NO barriers (per-wave vmcnt pipelining).
__global__ __launch_bounds__(512, 4) void k_attn(
    const int* __restrict__ adj, const unsigned short* __restrict__ hT,
    const float* __restrict__ f1, const float* __restrict__ f2,
    const unsigned* __restrict__ gmax,
    float* __restrict__ Opart, float* __restrict__ lpart)
{
  const int s    = blockIdx.x;        // ksplit 0..7  (1024 k each)
  const int rb   = blockIdx.y;        // rowblock 0..63 (128 rows)
  const int tid  = threadIdx.x;
  const int w    = tid >> 6;          // wave 0..7
  const int lane = tid & 63;
  const int quad = lane >> 4;
  const int m    = lane & 15;
  const int i    = rb * 128 + w * 16 + m;   // this lane's P row
  const int k0   = s * 1024;

  __shared__ float4 sHT[4096];        // exactly 64KB: 128 cols x 32 k-octets, XOR swizzled

  const float F2MAX = fdec(*gmax);
  const float f1i = f1[i];
  const float mm = f1i + F2MAX;
  const float mi = fmaxf(mm, GAT_ALPHA * mm);  // lrelu(f1+maxf2) >= row max, exact bound
  const float L2E = 1.44269504089f;
  const float miL = mi * L2E;

  f32x4 acc[8];
  #pragma unroll
  for (int ct = 0; ct < 8; ++ct){ acc[ct][0]=0.f; acc[ct][1]=0.f; acc[ct][2]=0.f; acc[ct][3]=0.f; }
  float lp = 0.f;

  const int* arow = adj + (size_t)i * NR + k0 + quad * 8;

  i32x4 av[4], nv[4];

  // stage one 256-k phase of hT (64KB) into LDS, XOR-swizzled 16B blocks
  auto stageHT = [&](int ph){
    const size_t kb = (size_t)k0 + (size_t)ph * 256;
    #pragma unroll
    for (int q = 0; q < 8; ++q){
      int lin  = q * 512 + tid;       // 16B block index 0..4095
      int c    = lin >> 5;            // feature col 0..127
      int blk  = lin & 31;            // k-octet within phase
      int sblk = (blk & ~7) | ((blk & 7) ^ (c & 7));
      gload_lds16(hT + (size_t)c * NR + kb + (size_t)sblk * 8, &sHT[lin]);
    }
  };
  auto loadAdj = [&](int kc, i32x4* dst){
    const i32x4* p0 = (const i32x4*)(arow + kc * 64);
    #pragma unroll
    for (int ks = 0; ks < 2; ++ks){
      dst[2*ks]   = __builtin_nontemporal_load(p0 + ks*8);
      dst[2*ks+1] = __builtin_nontemporal_load(p0 + ks*8 + 1);
    }
  };

  stageHT(0);
  loadAdj(0, av);
  __syncthreads();

  for (int kc = 0; kc < 16; ++kc){
    if (kc && (kc & 3) == 0){         // phase boundary: 3 per kernel
      __syncthreads();                // everyone done reading old phase
      stageHT(kc >> 2);
      __syncthreads();                // new phase ready
    }
    if (kc < 15) loadAdj(kc + 1, nv); // register prefetch of next adj chunk

    // f2 for this chunk straight from global (4KB slice, L1-broadcast)
    const float4* f2g = (const float4*)(f2 + k0 + kc * 64);

    // P in A-frag layout: A[m=lane&15][k = ks*32 + quad*8 + j]
    short8 afr[2];
    #pragma unroll
    for (int ks = 0; ks < 2; ++ks){
      float4 fA = f2g[ks*8 + quad*2];
      float4 fB = f2g[ks*8 + quad*2 + 1];
      i32x4 aA = av[2*ks], aB = av[2*ks+1];
      float fv[8] = {fA.x, fA.y, fA.z, fA.w, fB.x, fB.y, fB.z, fB.w};
      int   ai[8] = {aA[0], aA[1], aA[2], aA[3], aB[0], aB[1], aB[2], aB[3]};
      short8 fr;
      #pragma unroll
      for (int j = 0; j < 8; ++j){
        float t = f1i + fv[j];
        float u = fmaxf(t, GAT_ALPHA * t);       // leaky relu
        float p = __builtin_amdgcn_exp2f(fmaf(u, L2E, -miL));   // exp(u-mi), <=1
        p = (ai[j] > 0) ? p : 0.f;
        lp += p;
        fr[j] = (short)f2bf(p);
      }
      afr[ks] = fr;
    }

    // 16 MFMAs: 2 K-steps x 8 col-tiles of 16; B from swizzled LDS
    const short8* sB = (const short8*)&sHT[0];
    #pragma unroll
    for (int ks = 0; ks < 2; ++ks){
      #pragma unroll
      for (int ct = 0; ct < 8; ++ct){
        int c = ct * 16 + m;
        int o = (kc & 3) * 8 + ks * 4 + quad;    // k-octet within phase 0..31
        int so = (o & ~7) | ((o & 7) ^ (c & 7));
        short8 bfr = sB[c * 32 + so];
        acc[ct] = __builtin_amdgcn_mfma_f32_16x16x32_bf16(afr[ks], bfr, acc[ct], 0, 0, 0);
      }
    }

    if (kc < 15){
      #pragma unroll
      for (int q = 0; q < 4; ++q) av[q] = nv[q];
    }
  }

  // ---- epilogue: per-split partial stores (no atomics) ----
  lp += __shfl_xor(lp, 16, 64);
  lp += __shfl_xor(lp, 32, 64);
  if (lane < 16) lpart[(size_t)s * NR + rb * 128 + w * 16 + m] = lp;

  float* op = Opart + (size_t)s * NR * DD;
  #pragma unroll
  for (int ct = 0; ct < 8; ++ct){
    int col = ct * 16 + m;
    #pragma unroll
    for (int reg = 0; reg < 4; ++reg){
      int row = rb * 128 + w * 16 + quad * 4 + reg;  // C layout: col=lane&15, row=quad*4+reg
      __builtin_nontemporal_store(acc[ct][reg], op + (size_t)row * DD + col);
    }
  }
}

// ---- k3: reduce split-K partials, out = elu(O / l) ----
__global__ __launch_bounds__(256) void k_out(
    const float* __restrict__ Opart, const float* __restrict__ lpart,
    float* __restrict__ out)
{
  const int gid = blockIdx.x * 256 + threadIdx.x;   // float4 index, 262144 total
  const int row = gid >> 5;
  float lsum = 0.f;
  float4 o = make_float4(0.f, 0.f, 0.f, 0.f);
  const float4* O4 = (const float4*)Opart;
  #pragma unroll
  for (int s = 0; s < NSPLIT; ++s){
    lsum += lpart[(size_t)s * NR + row];
    float4 v = O4[(size_t)s * (NR * DD / 4) + gid];
    o.x += v.x; o.y += v.y; o.z += v.z; o.w += v.w;
  }
  const float inv = 1.0f / lsum;
  float4 r; float x;
  x = o.x * inv; r.x = x > 0.f ? x : (__expf(x) - 1.f);
  x = o.y * inv; r.y = x > 0.f ? x : (__expf(x) - 1.f);
  x = o.z * inv; r.z = x > 0.f ? x : (__expf(x) - 1.f);
  x = o.w * inv; r.w = x > 0.f ? x : (__expf(x) - 1.f);
  ((float4*)out)[gid] = r;
}

// ---- launcher ----
extern "C" void kernel_launch(void* const* d_in, const int* in_sizes, int n_in,
                              void* d_out, int out_size, void* d_ws, size_t ws_size,
                              hipStream_t stream)
{
  const float* in  = (const float*)d_in[0];
  const int*   adj = (const int*)  d_in[1];
  const float* W   = (const float*)d_in[2];
  const float* a   = (const float*)d_in[3];
  float* out = (float*)d_out;

  char* ws = (char*)d_ws;
  // layout (bytes):
  //   gmax  [0, 4)
  //   f1    [4096,   36864)                 fp32 [8192]
  //   f2    [36864,  69632)                 fp32 [8192]
  //   hT    [1048576, 3145728)              bf16 [128][8192]
  //   Opart [4194304, 4194304+33554432)     fp32 [8][8192][128]
  //   lpart [37748736, 38010880)            fp32 [8][8192]
  unsigned*       gmax  = (unsigned*)      (ws + 0);
  float*          f1    = (float*)         (ws + 4096);
  float*          f2    = (float*)         (ws + 36864);
  unsigned short* hT    = (unsigned short*)(ws + 1048576);
  float*          Opart = (float*)         (ws + 4194304);
  float*          lpart = (float*)         (ws + 37748736);

  (void)hipMemsetAsync(gmax, 0, 4, stream);   // fenc-space -inf

  hipLaunchKernelGGL(k_pre,  dim3(1024),   dim3(256), 0, stream, in, W, a, hT, f1, f2, gmax);
  hipLaunchKernelGGL(k_attn, dim3(8, 64),  dim3(512), 0, stream, adj, hT, f1, f2, gmax, Opart, lpart);
  hipLaunchKernelGGL(k_out,  dim3(1024),   dim3(256), 0, stream, Opart, lpart, out);
}